// Round 6
// baseline (84.995 us; speedup 1.0000x reference)
//
#include <hip/hip_runtime.h>
#include <math.h>

#define NMAX   64
#define NSITES 12
#define BLOCK  256
#define EPB    64     // elements per block: one per lane; wave w owns sites 3w..3w+2
#define RS     68     // neighbor row stride (floats), 16B-aligned rows

#define B_SOFT 0.01f
#define PAD_C  14.0f  // sentinel coord: r2 in [~155,~740] -> negligible on both paths
#define TBL_LO 1392   // (bits>>19) of 2^-40
#define TBL_N  800    // 16 bins/octave lerp, r2 in [2^-40, 2^10); real r2 <= ~250
#define RAW_LO (TBL_LO * 8)   // 11136 = low bound of (bits>>16)&~7

#define NB_F   (NSITES * RS)          // 816
#define GW_NBX (2 * TBL_N)            // 1600
#define GW_NBY (GW_NBX + NB_F)        // 2416
#define GW_F   (GW_NBY + NB_F)        // 3232 floats

// LDS float layout: table [0,1600) | nbx [1600,2416) | nby [2416,3232) | part
#define L_NBX  (2 * TBL_N)
#define L_NBY  (L_NBX + NB_F)
#define L_PART (L_NBY + NB_F)
#define SMEM_F (L_PART + 3 * EPB)     // 3424 floats = 13696 B -> 8 blocks/CU

__device__ __align__(16) float g_ws[GW_F];
__device__ int g_mq[4];

typedef float v2f __attribute__((ext_vector_type(2)));
typedef float v4f __attribute__((ext_vector_type(4)));

// f(r2) = exp(-sqrt(r2)) / (sqrt(r2) + b), exact (init kernel only)
__device__ __forceinline__ float f_exact(float r2) {
    const float r = sqrtf(r2);
    return expf(-r) / (r + B_SOFT);
}

// One block, once per launch: build lerp table + ballot-compact neighbors.
__global__ void init_kernel(const float* __restrict__ neighbors,
                            const float* __restrict__ mask) {
    __shared__ int cnt[NSITES];
    const int tid  = threadIdx.x;
    const int wv   = tid >> 6;
    const int lane = tid & 63;

    // Piecewise-linear table: bin i covers r2-bits [ (i+LO)<<19, (i+LO+1)<<19 );
    // chord + midpoint correction halves the max lerp error.
    for (int i = tid; i < TBL_N; i += BLOCK) {
        const unsigned ii = (unsigned)(i + TBL_LO);
        const float b0 = __builtin_bit_cast(float, ii << 19);
        const float b1 = __builtin_bit_cast(float, (ii + 1u) << 19);
        const float f0 = f_exact(b0);
        const float f1 = f_exact(b1);
        const float fm = f_exact(0.5f * (b0 + b1));
        const float sl = (f1 - f0) / (b1 - b0);
        const float c  = f0 - sl * b0 - 0.5f * (0.5f * (f0 + f1) - fm);
        g_ws[2 * i]     = c;
        g_ws[2 * i + 1] = sl;
    }

    // Sentinel fill: slots past a site's count -> r2 in [155,740] -> f~3e-7.
    for (int i = tid; i < 2 * NB_F; i += BLOCK) g_ws[GW_NBX + i] = PAD_C;
    __syncthreads();

    for (int s = wv; s < NSITES; s += 4) {
        const bool keep = mask[s * NMAX + lane] > 0.5f;
        const unsigned long long bal = __ballot(keep);
        if (keep) {
            const int pos = __popcll(bal & ((1ull << lane) - 1ull));
            const float2 p = ((const float2*)neighbors)[s * NMAX + lane];
            g_ws[GW_NBX + s * RS + pos] = p.x;
            g_ws[GW_NBY + s * RS + pos] = p.y;
        }
        if (lane == 0) cnt[s] = __popcll(bal);
    }
    __syncthreads();
    if (tid < 4) {    // per-wave loop bound: max over that wave's 3 sites
        const int mm = max(cnt[3 * tid],
                       max(cnt[3 * tid + 1], cnt[3 * tid + 2]));
        g_mq[tid] = (mm + 3) & ~3;   // <= 64, RS-safe
    }
}

__global__ __launch_bounds__(BLOCK, 8)
void pot_energy_kernel(const float* __restrict__ x,
                       float* __restrict__ out, int B) {
    __shared__ __align__(16) float smem[SMEM_F];
    const int tid  = threadIdx.x;
    const int w    = tid >> 6;     // wave = site-quadrant (uniform per wave)
    const int lane = tid & 63;     // lane = element within the block

    // Prologue: copy table + compacted neighbors from L2-hot device global.
    {
        const float4* s4 = (const float4*)g_ws;
        float4* d4 = (float4*)smem;
        #pragma unroll
        for (int i0 = 0; i0 < 4; ++i0) {
            const int i = tid + i0 * BLOCK;
            if (i < GW_F / 4) d4[i] = s4[i];
        }
    }
    const int q = __builtin_amdgcn_readfirstlane(w);
    const int m = g_mq[q];         // wave-uniform -> scalar load
    __syncthreads();

    const int e  = blockIdx.x * EPB + lane;
    const int el = (e < B) ? e : 0;

    // This wave's 3 site positions for element e: 6 contiguous floats.
    const float* xb = x + (size_t)el * 24 + q * 6;
    const float2 pa = ((const float2*)xb)[0];
    const float2 pb = ((const float2*)xb)[1];
    const float2 pc = ((const float2*)xb)[2];
    const float xs_[3] = { pa.x, pb.x, pc.x };
    const float ys_[3] = { pa.y, pb.y, pc.y };

    const char* tb = (const char*)smem - RAW_LO;   // tb + raw indexes table
    const v2f eps2 = { 9.094947e-13f, 9.094947e-13f };   // 2^-40 floor, in-fma
    const float NLOG2E = -1.4426950408889634f;           // -log2(e)

    // HYBRID pipe split: per 4-neighbor chunk, k=0,1 -> LDS table gather,
    // k=2,3 -> direct trans eval (v_sqrt/v_exp/v_rcp).  Gather wave-ops on
    // the CU-shared LDS pipe halve (the invariant dominator of R0..R5);
    // the trans half rides the otherwise-idle quarter-rate trans pipe.
    float accC = 0.f, accS = 0.f;   // table path: sum(c), sum(s*r2)
    float accT0 = 0.f, accT1 = 0.f; // trans path: 2 fma chains
    #pragma unroll
    for (int s = 0; s < 3; ++s) {
        const int site = q * 3 + s;
        // All 64 lanes read the SAME address -> pure broadcast, conflict-free.
        const float* __restrict__ rx = smem + L_NBX + site * RS;
        const float* __restrict__ ry = smem + L_NBY + site * RS;
        const v2f xs2 = { xs_[s], xs_[s] };
        const v2f ys2 = { ys_[s], ys_[s] };
        #pragma unroll 2
        for (int j0 = 0; j0 < m; j0 += 4) {
            const v4f nx4 = *(const v4f*)(rx + j0);
            const v4f ny4 = *(const v4f*)(ry + j0);
            const v2f dxA = xs2 - nx4.xy;
            const v2f dxB = xs2 - nx4.zw;
            const v2f dyA = ys2 - ny4.xy;
            const v2f dyB = ys2 - ny4.zw;
            // eps folded into the fma chain: r2 >= 2^-40, no low clamp op
            const v2f r2A = __builtin_elementwise_fma(
                dyA, dyA, __builtin_elementwise_fma(dxA, dxA, eps2));
            const v2f r2B = __builtin_elementwise_fma(
                dyB, dyB, __builtin_elementwise_fma(dxB, dxB, eps2));
            const float r2k[4] = { r2A.x, r2A.y, r2B.x, r2B.y };

            #pragma unroll
            for (int k = 0; k < 2; ++k) {       // ---- table path ----
                const unsigned raw =
                    (__builtin_bit_cast(unsigned, r2k[k]) >> 16) & 0xFFF8u;
                const float2 cs = *(const float2*)(tb + raw);
                accC += cs.x;
                accS = fmaf(cs.y, r2k[k], accS);
            }
            #pragma unroll
            for (int k = 2; k < 4; ++k) {       // ---- trans path ----
                const float r  = __builtin_amdgcn_sqrtf(r2k[k]);
                const float ex = __builtin_amdgcn_exp2f(r * NLOG2E);
                const float rc = __builtin_amdgcn_rcpf(r + B_SOFT);
                if (k & 1) accT1 = fmaf(ex, rc, accT1);
                else       accT0 = fmaf(ex, rc, accT0);
            }
        }
    }

    // Combine the 4 wave-partials of each element via LDS.
    const float av = (accC + accS) + (accT0 + accT1);
    if (w != 0) smem[L_PART + (w - 1) * EPB + lane] = av;
    __syncthreads();
    if (w == 0 && e < B) {
        out[e] = av + smem[L_PART + lane]
                    + smem[L_PART + EPB + lane]
                    + smem[L_PART + 2 * EPB + lane];   // coalesced store
    }
}

extern "C" void kernel_launch(void* const* d_in, const int* in_sizes, int n_in,
                              void* d_out, int out_size, void* d_ws, size_t ws_size,
                              hipStream_t stream) {
    const float* x   = (const float*)d_in[0];
    const float* nbr = (const float*)d_in[1];
    const float* msk = (const float*)d_in[2];
    float* out = (float*)d_out;

    const int B = in_sizes[0] / 24;

    init_kernel<<<1, BLOCK, 0, stream>>>(nbr, msk);

    const int blocks = (B + EPB - 1) / EPB;
    pot_energy_kernel<<<blocks, BLOCK, 0, stream>>>(x, out, B);
}

// Round 7
// 82.539 us; speedup vs baseline: 1.0298x; 1.0298x over previous
//
#include <hip/hip_runtime.h>
#include <hip/hip_fp16.h>
#include <math.h>

#define NMAX   64
#define NSITES 12
#define BLOCK  256
#define EPB    64     // elements per block: one per lane; wave w owns sites 3w..3w+2
#define RS     68     // neighbor row stride (floats), 16B-aligned rows

#define B_SOFT 0.01f
#define PAD_C  14.0f  // sentinel coord: r2 in [~200,~650] -> f ~ 6e-8 (in-table)
#define TBL_LO 1392   // (bits>>19) of 2^-40
#define TBL_N  800    // 16 bins/octave lerp, r2 in [2^-40, 2^10); real r2 <= ~250
#define RAW_LO4 (TBL_LO * 4)  // byte offset bias for (bits>>17)&~3 indexing

#define NB_F   (NSITES * RS)          // 816 floats per coord array

// Device-global scratch: f16x2 table + compacted SoA neighbors.
__device__ __align__(16) __half2 g_tbl[TBL_N];          // (c, s) per bin
__device__ __align__(16) float   g_nb[2 * NB_F];        // nbx | nby
__device__ int g_mq[4];

// LDS float layout: table [0,800) (as __half2) | nbx | nby | partials
#define L_NBX  TBL_N
#define L_NBY  (L_NBX + NB_F)
#define L_PART (L_NBY + NB_F)
#define SMEM_F (L_PART + 3 * EPB)     // 2624 floats = 10496 B -> 8 blocks/CU

typedef float v2f __attribute__((ext_vector_type(2)));
typedef float v4f __attribute__((ext_vector_type(4)));

// f(r2) = exp(-sqrt(r2)) / (sqrt(r2) + b), exact (init kernel only)
__device__ __forceinline__ float f_exact(float r2) {
    const float r = sqrtf(r2);
    return expf(-r) / (r + B_SOFT);
}

// One block, once per launch: build f16 lerp table + ballot-compact neighbors.
__global__ void init_kernel(const float* __restrict__ neighbors,
                            const float* __restrict__ mask) {
    __shared__ int cnt[NSITES];
    const int tid  = threadIdx.x;
    const int wv   = tid >> 6;
    const int lane = tid & 63;

    // Piecewise-linear table: bin i covers r2-bits [ (i+LO)<<19, (i+LO+1)<<19 );
    // chord + midpoint correction.  Slope clamped to f16 range: for tiny-r2
    // bins the s*r2 term is ~1e-7, so clamping costs ~4e-3 absolute (noise).
    for (int i = tid; i < TBL_N; i += BLOCK) {
        const unsigned ii = (unsigned)(i + TBL_LO);
        const float b0 = __builtin_bit_cast(float, ii << 19);
        const float b1 = __builtin_bit_cast(float, (ii + 1u) << 19);
        const float f0 = f_exact(b0);
        const float f1 = f_exact(b1);
        const float fm = f_exact(0.5f * (b0 + b1));
        float sl = (f1 - f0) / (b1 - b0);
        sl = fminf(fmaxf(sl, -60000.f), 60000.f);       // f16-safe
        const float c  = f0 - sl * b0 - 0.5f * (0.5f * (f0 + f1) - fm);
        __half2 h;
        h.x = __float2half_rn(c);
        h.y = __float2half_rn(sl);
        g_tbl[i] = h;
    }

    // Sentinel fill: slots past a site's count -> r2 in [200,650] -> f~6e-8.
    for (int i = tid; i < 2 * NB_F; i += BLOCK) g_nb[i] = PAD_C;
    __syncthreads();

    for (int s = wv; s < NSITES; s += 4) {
        const bool keep = mask[s * NMAX + lane] > 0.5f;
        const unsigned long long bal = __ballot(keep);
        if (keep) {
            const int pos = __popcll(bal & ((1ull << lane) - 1ull));
            const float2 p = ((const float2*)neighbors)[s * NMAX + lane];
            g_nb[s * RS + pos]        = p.x;
            g_nb[NB_F + s * RS + pos] = p.y;
        }
        if (lane == 0) cnt[s] = __popcll(bal);
    }
    __syncthreads();
    if (tid < 4) {    // per-wave loop bound: max over that wave's 3 sites
        const int mm = max(cnt[3 * tid],
                       max(cnt[3 * tid + 1], cnt[3 * tid + 2]));
        g_mq[tid] = (mm + 3) & ~3;   // <= 64, RS-safe
    }
}

__global__ __launch_bounds__(BLOCK, 8)
void pot_energy_kernel(const float* __restrict__ x,
                       float* __restrict__ out, int B) {
    __shared__ __align__(16) float smem[SMEM_F];
    const int tid  = threadIdx.x;
    const int w    = tid >> 6;     // wave = site-quadrant (uniform per wave)
    const int lane = tid & 63;     // lane = element within the block

    // Prologue: copy f16 table + compacted neighbors from L2-hot globals.
    {
        const float4* s4 = (const float4*)g_tbl;   // 800 halves2 = 200 f4
        float4* d4 = (float4*)smem;
        if (tid < TBL_N / 4) d4[tid] = s4[tid];
        const float4* n4 = (const float4*)g_nb;    // 2*816 floats = 408 f4
        float4* e4 = (float4*)(smem + L_NBX);
        #pragma unroll
        for (int i0 = 0; i0 < 2; ++i0) {
            const int i = tid + i0 * BLOCK;
            if (i < (2 * NB_F) / 4) e4[i] = n4[i];
        }
    }
    const int q = __builtin_amdgcn_readfirstlane(w);
    const int m = g_mq[q];         // wave-uniform -> scalar load
    __syncthreads();

    const int e  = blockIdx.x * EPB + lane;
    const int el = (e < B) ? e : 0;

    // This wave's 3 site positions for element e: 6 contiguous floats.
    const float* xb = x + (size_t)el * 24 + q * 6;
    const float2 pa = ((const float2*)xb)[0];
    const float2 pb = ((const float2*)xb)[1];
    const float2 pc = ((const float2*)xb)[2];
    const float xs_[3] = { pa.x, pb.x, pc.x };
    const float ys_[3] = { pa.y, pb.y, pc.y };

    // tb + ((bits>>17)&~3) indexes the f16x2 table (4B entries, b32 gather:
    // 32 bank-touches per 32-lane phase vs 64 for the old b64 -> ~3x less
    // conflict serialization on the CU-shared LDS pipe).
    const char* tb = (const char*)smem - RAW_LO4;
    const v2f eps2 = { 9.094947e-13f, 9.094947e-13f };   // 2^-40 floor, in-fma

    float accC = 0.f, accS = 0.f;   // sum(c_i) and sum(s_i * r2_i)
    #pragma unroll
    for (int s = 0; s < 3; ++s) {
        const int site = q * 3 + s;
        // All 64 lanes read the SAME address -> pure broadcast, conflict-free.
        const float* __restrict__ rx = smem + L_NBX + site * RS;
        const float* __restrict__ ry = smem + L_NBY + site * RS;
        const v2f xs2 = { xs_[s], xs_[s] };
        const v2f ys2 = { ys_[s], ys_[s] };
        #pragma unroll 2
        for (int j0 = 0; j0 < m; j0 += 4) {
            const v4f nx4 = *(const v4f*)(rx + j0);
            const v4f ny4 = *(const v4f*)(ry + j0);
            const v2f dxA = xs2 - nx4.xy;
            const v2f dxB = xs2 - nx4.zw;
            const v2f dyA = ys2 - ny4.xy;
            const v2f dyB = ys2 - ny4.zw;
            // eps folded into the fma chain: r2 >= 2^-40, no low clamp op
            const v2f r2A = __builtin_elementwise_fma(
                dyA, dyA, __builtin_elementwise_fma(dxA, dxA, eps2));
            const v2f r2B = __builtin_elementwise_fma(
                dyB, dyB, __builtin_elementwise_fma(dxB, dxB, eps2));
            const float r2k[4] = { r2A.x, r2A.y, r2B.x, r2B.y };
            #pragma unroll
            for (int k = 0; k < 4; ++k) {
                const unsigned raw =
                    (__builtin_bit_cast(unsigned, r2k[k]) >> 17) & 0xFFFCu;
                const __half2 h2 = *(const __half2*)(tb + raw);  // ds_read_b32
                const float2 cs = __half22float2(h2);
                accC += cs.x;
                accS = fmaf(cs.y, r2k[k], accS);
            }
        }
    }

    // Combine the 4 wave-partials of each element via LDS.
    const float av = accC + accS;
    if (w != 0) smem[L_PART + (w - 1) * EPB + lane] = av;
    __syncthreads();
    if (w == 0 && e < B) {
        out[e] = av + smem[L_PART + lane]
                    + smem[L_PART + EPB + lane]
                    + smem[L_PART + 2 * EPB + lane];   // coalesced store
    }
}

extern "C" void kernel_launch(void* const* d_in, const int* in_sizes, int n_in,
                              void* d_out, int out_size, void* d_ws, size_t ws_size,
                              hipStream_t stream) {
    const float* x   = (const float*)d_in[0];
    const float* nbr = (const float*)d_in[1];
    const float* msk = (const float*)d_in[2];
    float* out = (float*)d_out;

    const int B = in_sizes[0] / 24;

    init_kernel<<<1, BLOCK, 0, stream>>>(nbr, msk);

    const int blocks = (B + EPB - 1) / EPB;
    pot_energy_kernel<<<blocks, BLOCK, 0, stream>>>(x, out, B);
}

// Round 8
// 79.373 us; speedup vs baseline: 1.0708x; 1.0399x over previous
//
#include <hip/hip_runtime.h>
#include <math.h>

#define NMAX   64
#define NSITES 12
#define BLOCK  256
#define EPB    64     // elements per block: one per lane; wave w owns sites 3w..3w+2
#define RS     68     // neighbor row stride (floats); rows 16B-aligned

#define B_SOFT 0.01f
#define PAD_C  14.0f  // sentinel coord: r2 in [~155,~740] -> f ~ 3e-7, inside table
#define TBL_LO 1392   // (bits>>19) of 2^-40
#define TBL_N  800    // 16 bins/octave lerp, r2 in [2^-40, 2^10); real r2 <= ~250
#define RAW_LO (TBL_LO * 8)   // 11136 = low bound of (bits>>16)&~7

#define NB_F   (NSITES * RS)          // 816 floats per coord array

// Device-global: f32 (c,s) lerp table + compacted SoA neighbors.
// Neighbors are read DIRECTLY from here in the main loop with wave-uniform
// addresses -> scalar loads (s_load_dwordx4 via constant cache), taking the
// 2x ds_read_b128/chunk (24 cyc, ~40% of the LDS pipe budget) OFF the
// CU-shared LDS pipe.  LDS carries only the random table gather.
__device__ __align__(16) float2 g_tbl[TBL_N];
__device__ __align__(16) float  g_nb[2 * NB_F];
__device__ int g_mq[4];

// LDS float layout: table [0,1600) | partials [1600,1792)
#define L_PART (2 * TBL_N)
#define SMEM_F (L_PART + 3 * EPB)     // 1792 floats = 7168 B -> 8 blocks/CU

typedef float v2f __attribute__((ext_vector_type(2)));
typedef float v4f __attribute__((ext_vector_type(4)));

// f(r2) = exp(-sqrt(r2)) / (sqrt(r2) + b), exact (init kernel only)
__device__ __forceinline__ float f_exact(float r2) {
    const float r = sqrtf(r2);
    return expf(-r) / (r + B_SOFT);
}

// One block, once per launch: build lerp table + ballot-compact neighbors.
__global__ void init_kernel(const float* __restrict__ neighbors,
                            const float* __restrict__ mask) {
    __shared__ int cnt[NSITES];
    const int tid  = threadIdx.x;
    const int wv   = tid >> 6;
    const int lane = tid & 63;

    // Piecewise-linear table: bin i covers r2-bits [ (i+LO)<<19, (i+LO+1)<<19 );
    // chord + midpoint correction halves the max lerp error.
    for (int i = tid; i < TBL_N; i += BLOCK) {
        const unsigned ii = (unsigned)(i + TBL_LO);
        const float b0 = __builtin_bit_cast(float, ii << 19);
        const float b1 = __builtin_bit_cast(float, (ii + 1u) << 19);
        const float f0 = f_exact(b0);
        const float f1 = f_exact(b1);
        const float fm = f_exact(0.5f * (b0 + b1));
        const float sl = (f1 - f0) / (b1 - b0);
        const float c  = f0 - sl * b0 - 0.5f * (0.5f * (f0 + f1) - fm);
        g_tbl[i] = make_float2(c, sl);
    }

    // Sentinel fill: slots past a site's count -> r2 in [155,740] -> f~3e-7.
    for (int i = tid; i < 2 * NB_F; i += BLOCK) g_nb[i] = PAD_C;
    __syncthreads();

    for (int s = wv; s < NSITES; s += 4) {
        const bool keep = mask[s * NMAX + lane] > 0.5f;
        const unsigned long long bal = __ballot(keep);
        if (keep) {
            const int pos = __popcll(bal & ((1ull << lane) - 1ull));
            const float2 p = ((const float2*)neighbors)[s * NMAX + lane];
            g_nb[s * RS + pos]        = p.x;
            g_nb[NB_F + s * RS + pos] = p.y;
        }
        if (lane == 0) cnt[s] = __popcll(bal);
    }
    __syncthreads();
    if (tid < 4) {    // per-wave loop bound: max over that wave's 3 sites
        const int mm = max(cnt[3 * tid],
                       max(cnt[3 * tid + 1], cnt[3 * tid + 2]));
        g_mq[tid] = (mm + 3) & ~3;   // <= 64, RS-safe
    }
}

__global__ __launch_bounds__(BLOCK, 8)
void pot_energy_kernel(const float* __restrict__ x,
                       float* __restrict__ out, int B) {
    __shared__ __align__(16) float smem[SMEM_F];
    const int tid  = threadIdx.x;
    const int w    = tid >> 6;     // wave = site-quadrant (uniform per wave)
    const int lane = tid & 63;     // lane = element within the block

    // Prologue: copy ONLY the table into LDS (6.4 KB).
    {
        const float4* s4 = (const float4*)g_tbl;   // 800 float2 = 400 f4
        float4* d4 = (float4*)smem;
        #pragma unroll
        for (int i0 = 0; i0 < 2; ++i0) {
            const int i = tid + i0 * BLOCK;
            if (i < (2 * TBL_N) / 4) d4[i] = s4[i];
        }
    }
    const int q = __builtin_amdgcn_readfirstlane(w);
    const int m = g_mq[q];         // wave-uniform -> scalar load
    __syncthreads();

    const int e  = blockIdx.x * EPB + lane;
    const int el = (e < B) ? e : 0;

    // This wave's 3 site positions for element e: 6 contiguous floats.
    const float* xb = x + (size_t)el * 24 + q * 6;
    const float2 pa = ((const float2*)xb)[0];
    const float2 pb = ((const float2*)xb)[1];
    const float2 pc = ((const float2*)xb)[2];
    const float xs_[3] = { pa.x, pb.x, pc.x };
    const float ys_[3] = { pa.y, pb.y, pc.y };

    const char* tb = (const char*)smem - RAW_LO;   // tb + raw indexes table
    const v2f eps2 = { 9.094947e-13f, 9.094947e-13f };   // 2^-40 floor, in-fma

    float accC = 0.f, accS = 0.f;   // sum(c_i) and sum(s_i * r2_i)
    #pragma unroll
    for (int s = 0; s < 3; ++s) {
        const int site = q * 3 + s;
        // Wave-uniform global addresses -> scalar (SMEM) loads through the
        // constant cache: NOT on the LDS pipe, NOT on the VMEM gather path.
        const float* __restrict__ rx = g_nb + site * RS;
        const float* __restrict__ ry = rx + NB_F;
        const v2f xs2 = { xs_[s], xs_[s] };
        const v2f ys2 = { ys_[s], ys_[s] };
        #pragma unroll 2
        for (int j0 = 0; j0 < m; j0 += 4) {
            const v4f nx4 = *(const v4f*)(rx + j0);   // s_load_dwordx4
            const v4f ny4 = *(const v4f*)(ry + j0);   // s_load_dwordx4
            const v2f dxA = xs2 - nx4.xy;
            const v2f dxB = xs2 - nx4.zw;
            const v2f dyA = ys2 - ny4.xy;
            const v2f dyB = ys2 - ny4.zw;
            // eps folded into the fma chain: r2 >= 2^-40, no low clamp op
            const v2f r2A = __builtin_elementwise_fma(
                dyA, dyA, __builtin_elementwise_fma(dxA, dxA, eps2));
            const v2f r2B = __builtin_elementwise_fma(
                dyB, dyB, __builtin_elementwise_fma(dxB, dxB, eps2));
            const float r2k[4] = { r2A.x, r2A.y, r2B.x, r2B.y };
            #pragma unroll
            for (int k = 0; k < 4; ++k) {
                // no clamps: real r2 <= ~250, sentinel <= ~740, table to 1024
                const unsigned raw =
                    (__builtin_bit_cast(unsigned, r2k[k]) >> 16) & 0xFFF8u;
                const float2 cs = *(const float2*)(tb + raw);  // ds_read_b64
                accC += cs.x;
                accS = fmaf(cs.y, r2k[k], accS);
            }
        }
    }

    // Combine the 4 wave-partials of each element via LDS.
    const float av = accC + accS;
    if (w != 0) smem[L_PART + (w - 1) * EPB + lane] = av;
    __syncthreads();
    if (w == 0 && e < B) {
        out[e] = av + smem[L_PART + lane]
                    + smem[L_PART + EPB + lane]
                    + smem[L_PART + 2 * EPB + lane];   // coalesced store
    }
}

extern "C" void kernel_launch(void* const* d_in, const int* in_sizes, int n_in,
                              void* d_out, int out_size, void* d_ws, size_t ws_size,
                              hipStream_t stream) {
    const float* x   = (const float*)d_in[0];
    const float* nbr = (const float*)d_in[1];
    const float* msk = (const float*)d_in[2];
    float* out = (float*)d_out;

    const int B = in_sizes[0] / 24;

    init_kernel<<<1, BLOCK, 0, stream>>>(nbr, msk);

    const int blocks = (B + EPB - 1) / EPB;
    pot_energy_kernel<<<blocks, BLOCK, 0, stream>>>(x, out, B);
}